// Round 6
// baseline (366.478 us; speedup 1.0000x reference)
//
#include <hip/hip_runtime.h>
#include <math.h>

#define H    2048
#define H3   6144
#define DIN  1024
#define DOUT 1024
#define NL   4
#define NB   512                  // 2 blocks/CU of capacity 4 -> safe co-residency
#define BT   256                  // 4 waves/block
#define NW   (NB * (BT / 64))     // 2048 waves

__device__ __forceinline__ float wave_reduce_sum(float v) {
    #pragma unroll
    for (int off = 32; off; off >>= 1) v += __shfl_down(v, off);
    return v;
}
__device__ __forceinline__ float dot4(float4 w, float4 v, float a) {
    return fmaf(w.x, v.x, fmaf(w.y, v.y, fmaf(w.z, v.z, fmaf(w.w, v.w, a))));
}

// Device-scope grid barrier: monotone counter, one atomicAdd per block.
// __threadfence() (agent scope) before the increment publishes this block's
// writes; the acquire fence after the spin invalidates caches so we see
// other XCDs' writes. Counter is monotone -> no reset races across phases.
__device__ __forceinline__ void grid_barrier(int* cnt, int target) {
    __syncthreads();
    if (threadIdx.x == 0) {
        __threadfence();   // release: publish block's writes device-wide
        __hip_atomic_fetch_add(cnt, 1, __ATOMIC_RELAXED, __HIP_MEMORY_SCOPE_AGENT);
        while (__hip_atomic_load(cnt, __ATOMIC_RELAXED, __HIP_MEMORY_SCOPE_AGENT) < target)
            __builtin_amdgcn_s_sleep(2);
    }
    __syncthreads();
    __builtin_amdgcn_fence(__ATOMIC_ACQUIRE, "agent");   // invalidate for reads
}

// Persistent kernel:
//  Phase 0: encoder rows (2048, K=1024) + ALL layers' gh rows (24576, K=2048)
//  Phase 1..4: per-layer W_ih dots over carry + fused gate math
//  Phase 5: decoder (1024 rows, K=2048)
__global__ __launch_bounds__(BT, 4) void gru_mono(
    const float* __restrict__ x,    const float* __restrict__ h0,
    const float* __restrict__ encW, const float* __restrict__ encb,
    const float* __restrict__ Wih,  const float* __restrict__ Whh,
    const float* __restrict__ bih,  const float* __restrict__ bhh,
    const float* __restrict__ decW, const float* __restrict__ decb,
    float* __restrict__ out,        float* __restrict__ ws,
    int* __restrict__ cnt)
{
    float* vec0 = ws;           // [H] carry ping
    float* vec1 = ws + H;       // [H] carry pong
    float* gh   = ws + 2 * H;   // [NL*3H] hh-gate precompute (includes b_hh)

    const int tid  = threadIdx.x;
    const int lane = tid & 63;
    const int wid  = tid >> 6;
    const int gw   = blockIdx.x * (BT / 64) + wid;

    __shared__ float part[4][3];

    // ---------------- Phase 0: enc + gh (13 rows/wave) ----------------
    for (int j = gw; j < 2048 + NL * H3; j += NW) {
        if (j < 2048) {
            const float* rp = encW + (size_t)j * DIN;
            float acc = 0.f;
            #pragma unroll
            for (int p = 0; p < DIN / 256; ++p) {
                int idx = p * 256 + lane * 4;
                acc = dot4(*reinterpret_cast<const float4*>(rp + idx),
                           *reinterpret_cast<const float4*>(x + idx), acc);
            }
            acc = wave_reduce_sum(acc);
            if (lane == 0) vec0[j] = acc + encb[j];
        } else {
            int g = j - 2048;
            int l = g / H3;
            const float* rp = Whh + (size_t)g * H;   // contiguous [NL*3H, H]
            const float* hv = h0 + l * H;
            float acc = 0.f;
            #pragma unroll
            for (int p = 0; p < H / 256; ++p) {
                int idx = p * 256 + lane * 4;
                acc = dot4(*reinterpret_cast<const float4*>(rp + idx),
                           *reinterpret_cast<const float4*>(hv + idx), acc);
            }
            acc = wave_reduce_sum(acc);
            if (lane == 0) gh[g] = acc + bhh[g];
        }
    }
    grid_barrier(cnt, 1 * NB);

    // ---------------- Phases 1..4 (layers) ----------------
    // r2 in [0, 2*H): row e = r2>>1, K-half = (r2&1)*1024. Wave pairs
    // (wid 0,1) and (wid 2,3) share a row; LDS-combine; lane0 of even wid
    // does the gate math. NW | 2*H -> all waves iterate in lockstep.
    const float* cin = vec0;
    float* cout = vec1;
    for (int l = 0; l < NL; ++l) {
        const float* Wl = Wih + (size_t)l * H3 * H;
        const float* bl = bih + (size_t)l * H3;
        const float* gl = gh + (size_t)l * H3;
        for (int r2 = gw; r2 < 2 * H; r2 += NW) {
            const int e    = r2 >> 1;
            const int base = (r2 & 1) * 1024;
            const float* r0 = Wl + (size_t)e * H;
            const float* r1 = Wl + (size_t)(e + H) * H;
            const float* rn = Wl + (size_t)(e + 2 * H) * H;
            float a0 = 0.f, a1 = 0.f, a2 = 0.f;
            #pragma unroll
            for (int p = 0; p < 4; ++p) {
                int idx = base + p * 256 + lane * 4;
                float4 v = *reinterpret_cast<const float4*>(cin + idx);
                a0 = dot4(*reinterpret_cast<const float4*>(r0 + idx), v, a0);
                a1 = dot4(*reinterpret_cast<const float4*>(r1 + idx), v, a1);
                a2 = dot4(*reinterpret_cast<const float4*>(rn + idx), v, a2);
            }
            a0 = wave_reduce_sum(a0);
            a1 = wave_reduce_sum(a1);
            a2 = wave_reduce_sum(a2);
            if (lane == 0) { part[wid][0] = a0; part[wid][1] = a1; part[wid][2] = a2; }
            __syncthreads();
            if ((wid & 1) == 0 && lane == 0) {
                float ir  = part[wid][0] + part[wid + 1][0] + bl[e];
                float iz  = part[wid][1] + part[wid + 1][1] + bl[H + e];
                float inn = part[wid][2] + part[wid + 1][2] + bl[2 * H + e];
                float r = 1.f / (1.f + expf(-(ir + gl[e])));
                float z = 1.f / (1.f + expf(-(iz + gl[H + e])));
                float n = tanhf(inn + r * gl[2 * H + e]);
                float h = h0[l * H + e];
                float hnew = (1.f - z) * n + z * h;
                cout[e] = hnew;
                out[DOUT + l * H + e] = hnew;   // hidden output slice
            }
            __syncthreads();   // WAR on part[] before next r2 iteration
        }
        grid_barrier(cnt, (2 + l) * NB);
        const float* t = cin; cin = cout; cout = (float*)t;
    }

    // ---------------- Phase 5: decoder (wave per row) ----------------
    for (int row = gw; row < DOUT; row += NW) {
        const float* rp = decW + (size_t)row * H;
        float acc = 0.f;
        #pragma unroll
        for (int p = 0; p < H / 256; ++p) {
            int idx = p * 256 + lane * 4;
            acc = dot4(*reinterpret_cast<const float4*>(rp + idx),
                       *reinterpret_cast<const float4*>(cin + idx), acc);
        }
        acc = wave_reduce_sum(acc);
        if (lane == 0) out[row] = acc + decb[row];
    }
}

extern "C" void kernel_launch(void* const* d_in, const int* in_sizes, int n_in,
                              void* d_out, int out_size, void* d_ws, size_t ws_size,
                              hipStream_t stream) {
    const float* x    = (const float*)d_in[0];
    const float* h0   = (const float*)d_in[1];
    const float* encW = (const float*)d_in[2];
    const float* encb = (const float*)d_in[3];
    const float* Wih  = (const float*)d_in[4];
    const float* Whh  = (const float*)d_in[5];
    const float* bih  = (const float*)d_in[6];
    const float* bhh  = (const float*)d_in[7];
    const float* decW = (const float*)d_in[8];
    const float* decb = (const float*)d_in[9];
    float* out = (float*)d_out;
    float* ws  = (float*)d_ws;

    // Barrier counter at 1 MB into ws (vectors+gh use first ~115 KB).
    int* cnt = (int*)((char*)d_ws + (1 << 20));
    (void)hipMemsetAsync((void*)cnt, 0, 64, stream);   // fresh barrier state every call

    gru_mono<<<NB, BT, 0, stream>>>(x, h0, encW, encb, Wih, Whh, bih, bhh,
                                    decW, decb, out, ws, cnt);
}

// Round 7
// 309.124 us; speedup vs baseline: 1.1855x; 1.1855x over previous
//
#include <hip/hip_runtime.h>
#include <math.h>

#define H    2048
#define H3   6144
#define DIN  1024
#define DOUT 1024
#define NL   4
#define NB   1024                 // 4 blocks/CU (capacity 8 at 256 thr, VGPR~52) -> 2x margin
#define BT   256                  // 4 waves/block
#define NWAVE (NB * (BT / 64))    // 4096 waves

__device__ __forceinline__ float wave_reduce_sum(float v) {
    #pragma unroll
    for (int off = 32; off; off >>= 1) v += __shfl_down(v, off);
    return v;
}
__device__ __forceinline__ float dot4(float4 w, float4 v, float a) {
    return fmaf(w.x, v.x, fmaf(w.y, v.y, fmaf(w.z, v.z, fmaf(w.w, v.w, a))));
}

// All RW-shared data (carry vectors, gh, counter) goes through agent-scope
// relaxed atomics -> sc1 path, coherent at the Infinity Cache, bypassing the
// non-coherent per-XCD L2s. This removes the need for any buffer_wbl2 /
// buffer_inv fences (R6 post-mortem: per-block __threadfence L2 flushes at
// every barrier cost ~370 us). Weights are read-only -> normal cached loads.
__device__ __forceinline__ float ld_coh(const float* p) {
    return __hip_atomic_load(p, __ATOMIC_RELAXED, __HIP_MEMORY_SCOPE_AGENT);
}
__device__ __forceinline__ void st_coh(float* p, float v) {
    __hip_atomic_store(p, v, __ATOMIC_RELAXED, __HIP_MEMORY_SCOPE_AGENT);
}

// Fence-free grid barrier. The leading __syncthreads drains every thread's
// outstanding stores (compiler emits s_waitcnt vmcnt(0) before s_barrier),
// so all sc1 stores are at the coherence point before the counter add.
__device__ __forceinline__ void grid_barrier(int* cnt, int target) {
    __syncthreads();
    if (threadIdx.x == 0) {
        __hip_atomic_fetch_add(cnt, 1, __ATOMIC_RELAXED, __HIP_MEMORY_SCOPE_AGENT);
        while (__hip_atomic_load(cnt, __ATOMIC_RELAXED, __HIP_MEMORY_SCOPE_AGENT) < target)
            __builtin_amdgcn_s_sleep(2);
    }
    __syncthreads();
}

// Persistent kernel:
//  Phase 0: encoder rows + all layers' gh rows (with exact-zero h0 chunk skip)
//  Phase 1..4: per-layer W_ih dots over carry + fused gate math
//  Phase 5: decoder
__global__ __launch_bounds__(BT, 4) void gru_mono(
    const float* __restrict__ x,    const float* __restrict__ h0,
    const float* __restrict__ encW, const float* __restrict__ encb,
    const float* __restrict__ Wih,  const float* __restrict__ Whh,
    const float* __restrict__ bih,  const float* __restrict__ bhh,
    const float* __restrict__ decW, const float* __restrict__ decb,
    float* __restrict__ out,        float* __restrict__ ws,
    int* __restrict__ cnt)
{
    float* vec0 = ws;           // [H] carry ping   (sc1-only access)
    float* vec1 = ws + H;       // [H] carry pong   (sc1-only access)
    float* gh   = ws + 2 * H;   // [NL*3H] hh gates (sc1-only access)

    const int tid  = threadIdx.x;
    const int lane = tid & 63;
    const int wid  = tid >> 6;
    const int gw   = blockIdx.x * (BT / 64) + wid;

    __shared__ float part[4][3];

    // ---------------- Phase 0: enc rows + gh rows ----------------
    for (int j = gw; j < 2048 + NL * H3; j += NWAVE) {
        if (j < 2048) {
            const float* rp = encW + (size_t)j * DIN;
            float acc = 0.f;
            #pragma unroll
            for (int p = 0; p < DIN / 256; ++p) {
                int idx = p * 256 + lane * 4;
                acc = dot4(*reinterpret_cast<const float4*>(rp + idx),
                           *reinterpret_cast<const float4*>(x + idx), acc);
            }
            acc = wave_reduce_sum(acc);
            if (lane == 0) st_coh(vec0 + j, acc + encb[j]);
        } else {
            int g = j - 2048;
            int l = g / H3;
            const float* rp = Whh + (size_t)g * H;   // contiguous [NL*3H, H]
            const float* hv = h0 + l * H;
            float acc = 0.f;
            #pragma unroll
            for (int p = 0; p < H / 256; ++p) {
                int idx = p * 256 + lane * 4;
                float4 h4 = *reinterpret_cast<const float4*>(hv + idx);
                // Exact-zero chunk skip (input-adaptive, bit-identical result):
                // lanes with h4==0 contribute exactly 0; if the whole wave's
                // 1KB span is zero, skip the W_hh loads entirely.
                int nz = (h4.x != 0.f) || (h4.y != 0.f) ||
                         (h4.z != 0.f) || (h4.w != 0.f);
                if (__any(nz))
                    acc = dot4(*reinterpret_cast<const float4*>(rp + idx), h4, acc);
            }
            acc = wave_reduce_sum(acc);
            if (lane == 0) st_coh(gh + g, acc + bhh[g]);
        }
    }
    grid_barrier(cnt, 1 * NB);

    // ---------------- Phases 1..4 (layers) ----------------
    // Wave pair (wid 0,1) owns e=2b half0/1; (wid 2,3) owns e=2b+1.
    const float* cin = vec0;
    float* cout = vec1;
    for (int l = 0; l < NL; ++l) {
        const float* Wl = Wih + (size_t)l * H3 * H;
        const float* bl = bih + (size_t)l * H3;
        float* gl = gh + (size_t)l * H3;
        const int e    = 2 * blockIdx.x + (wid >> 1);
        const int base = (wid & 1) * 1024;
        const float* r0 = Wl + (size_t)e * H;
        const float* r1 = Wl + (size_t)(e + H) * H;
        const float* rn = Wl + (size_t)(e + 2 * H) * H;
        float a0 = 0.f, a1 = 0.f, a2 = 0.f;
        #pragma unroll
        for (int p = 0; p < 4; ++p) {
            int idx = base + p * 256 + lane * 4;
            float4 v;
            v.x = ld_coh(cin + idx);     v.y = ld_coh(cin + idx + 1);
            v.z = ld_coh(cin + idx + 2); v.w = ld_coh(cin + idx + 3);
            a0 = dot4(*reinterpret_cast<const float4*>(r0 + idx), v, a0);
            a1 = dot4(*reinterpret_cast<const float4*>(r1 + idx), v, a1);
            a2 = dot4(*reinterpret_cast<const float4*>(rn + idx), v, a2);
        }
        a0 = wave_reduce_sum(a0);
        a1 = wave_reduce_sum(a1);
        a2 = wave_reduce_sum(a2);
        if (lane == 0) { part[wid][0] = a0; part[wid][1] = a1; part[wid][2] = a2; }
        __syncthreads();
        if ((wid & 1) == 0 && lane == 0) {
            float ir  = part[wid][0] + part[wid + 1][0] + bl[e];
            float iz  = part[wid][1] + part[wid + 1][1] + bl[H + e];
            float inn = part[wid][2] + part[wid + 1][2] + bl[2 * H + e];
            float r = 1.f / (1.f + expf(-(ir + ld_coh(gl + e))));
            float z = 1.f / (1.f + expf(-(iz + ld_coh(gl + H + e))));
            float n = tanhf(inn + r * ld_coh(gl + 2 * H + e));
            float h = h0[l * H + e];
            float hnew = (1.f - z) * n + z * h;
            st_coh(cout + e, hnew);
            out[DOUT + l * H + e] = hnew;   // hidden output slice
        }
        grid_barrier(cnt, (2 + l) * NB);
        const float* t = cin; cin = cout; cout = (float*)t;
    }

    // ---------------- Phase 5: decoder (block per row, 4-wave split-K) ----
    {
        const int row = blockIdx.x;            // NB == DOUT
        const float* rp = decW + (size_t)row * H;
        float acc = 0.f;
        #pragma unroll
        for (int p = 0; p < 2; ++p) {
            int idx = wid * 512 + p * 256 + lane * 4;
            float4 v;
            v.x = ld_coh(cin + idx);     v.y = ld_coh(cin + idx + 1);
            v.z = ld_coh(cin + idx + 2); v.w = ld_coh(cin + idx + 3);
            acc = dot4(*reinterpret_cast<const float4*>(rp + idx), v, acc);
        }
        acc = wave_reduce_sum(acc);
        if (lane == 0) part[wid][0] = acc;
        __syncthreads();
        if (tid == 0)
            out[row] = part[0][0] + part[1][0] + part[2][0] + part[3][0] + decb[row];
    }
}

extern "C" void kernel_launch(void* const* d_in, const int* in_sizes, int n_in,
                              void* d_out, int out_size, void* d_ws, size_t ws_size,
                              hipStream_t stream) {
    const float* x    = (const float*)d_in[0];
    const float* h0   = (const float*)d_in[1];
    const float* encW = (const float*)d_in[2];
    const float* encb = (const float*)d_in[3];
    const float* Wih  = (const float*)d_in[4];
    const float* Whh  = (const float*)d_in[5];
    const float* bih  = (const float*)d_in[6];
    const float* bhh  = (const float*)d_in[7];
    const float* decW = (const float*)d_in[8];
    const float* decb = (const float*)d_in[9];
    float* out = (float*)d_out;
    float* ws  = (float*)d_ws;

    // Barrier counter at 1 MB into ws (vectors+gh use first ~115 KB).
    int* cnt = (int*)((char*)d_ws + (1 << 20));
    (void)hipMemsetAsync((void*)cnt, 0, 64, stream);   // fresh barrier state every call

    gru_mono<<<NB, BT, 0, stream>>>(x, h0, encW, encb, Wih, Whh, bih, bhh,
                                    decW, decb, out, ws, cnt);
}

// Round 8
// 53.112 us; speedup vs baseline: 6.9001x; 5.8202x over previous
//
#include <hip/hip_runtime.h>
#include <math.h>

#define H 2048
#define DIN 1024
#define DOUT 1024
#define NL 4

__device__ __forceinline__ float wave_reduce_sum(float v) {
    #pragma unroll
    for (int off = 32; off; off >>= 1) v += __shfl_down(v, off);
    return v;
}
__device__ __forceinline__ float dot4(float4 w, float4 v, float a) {
    return fmaf(w.x, v.x, fmaf(w.y, v.y, fmaf(w.z, v.z, fmaf(w.w, v.w, a))));
}

// Generic GEMV: y[r] = dot(W[r,:], x) + b[r]. One 64-lane wave per row.
template <int K>
__global__ __launch_bounds__(256) void gemv_kernel(
    const float* __restrict__ W, const float* __restrict__ x,
    const float* __restrict__ b, float* __restrict__ y, int N) {
    int wave = (blockIdx.x * blockDim.x + threadIdx.x) >> 6;
    int lane = threadIdx.x & 63;
    if (wave >= N) return;
    const float* row = W + (size_t)wave * K;
    float acc = 0.f;
    #pragma unroll
    for (int i = 0; i < K / 256; ++i) {
        int idx = i * 256 + lane * 4;
        acc = dot4(*reinterpret_cast<const float4*>(row + idx),
                   *reinterpret_cast<const float4*>(x + idx), acc);
    }
    acc = wave_reduce_sum(acc);
    if (lane == 0) y[wave] = acc + b[wave];
}

// Fused per-layer GRU step (R2 structure): one wave per output element,
// 6 dots ({r,z,n} x {W_ih over carry, W_hh over h0[l]}) + gate math.
// NEW vs R2: exact-zero chunk skip on the W_hh dots — if the wave's 1KB
// span of hprev is all zeros, those three weight loads are skipped
// (bit-identical: fmaf(w, 0, acc) == acc for finite w). Halves traffic
// for zero h0; correct for any h0.
__global__ __launch_bounds__(256) void gru_layer_kernel(
    const float* __restrict__ Wi,    // [3H, H] this layer
    const float* __restrict__ Wh,    // [3H, H] this layer
    const float* __restrict__ bi,    // [3H]
    const float* __restrict__ bh,    // [3H]
    const float* __restrict__ hprev, // [H] = h0[l]
    const float* __restrict__ cin,   // [H]
    float* __restrict__ cout,        // [H]
    float* __restrict__ hid_out) {   // [H] slice of d_out
    int wave = (blockIdx.x * blockDim.x + threadIdx.x) >> 6;
    int lane = threadIdx.x & 63;
    if (wave >= H) return;
    const float* ir_row = Wi + (size_t)wave * H;
    const float* iz_row = Wi + (size_t)(wave + H) * H;
    const float* in_row = Wi + (size_t)(wave + 2 * H) * H;
    const float* hr_row = Wh + (size_t)wave * H;
    const float* hz_row = Wh + (size_t)(wave + H) * H;
    const float* hn_row = Wh + (size_t)(wave + 2 * H) * H;
    float air = 0.f, aiz = 0.f, ain = 0.f;
    float ahr = 0.f, ahz = 0.f, ahn = 0.f;
    #pragma unroll
    for (int i = 0; i < H / 256; ++i) {
        int idx = i * 256 + lane * 4;
        float4 xv = *reinterpret_cast<const float4*>(cin + idx);
        float4 hv = *reinterpret_cast<const float4*>(hprev + idx);
        air = dot4(*reinterpret_cast<const float4*>(ir_row + idx), xv, air);
        aiz = dot4(*reinterpret_cast<const float4*>(iz_row + idx), xv, aiz);
        ain = dot4(*reinterpret_cast<const float4*>(in_row + idx), xv, ain);
        int nz = (hv.x != 0.f) || (hv.y != 0.f) || (hv.z != 0.f) || (hv.w != 0.f);
        if (__any(nz)) {
            ahr = dot4(*reinterpret_cast<const float4*>(hr_row + idx), hv, ahr);
            ahz = dot4(*reinterpret_cast<const float4*>(hz_row + idx), hv, ahz);
            ahn = dot4(*reinterpret_cast<const float4*>(hn_row + idx), hv, ahn);
        }
    }
    air = wave_reduce_sum(air);
    aiz = wave_reduce_sum(aiz);
    ain = wave_reduce_sum(ain);
    ahr = wave_reduce_sum(ahr);
    ahz = wave_reduce_sum(ahz);
    ahn = wave_reduce_sum(ahn);
    if (lane == 0) {
        float ir  = air + bi[wave];
        float iz  = aiz + bi[H + wave];
        float inn = ain + bi[2 * H + wave];
        float hr  = ahr + bh[wave];
        float hz  = ahz + bh[H + wave];
        float hn  = ahn + bh[2 * H + wave];
        float r = 1.f / (1.f + expf(-(ir + hr)));
        float z = 1.f / (1.f + expf(-(iz + hz)));
        float n = tanhf(inn + r * hn);
        float h = hprev[wave];
        float hnew = (1.f - z) * n + z * h;
        cout[wave] = hnew;
        hid_out[wave] = hnew;
    }
}

extern "C" void kernel_launch(void* const* d_in, const int* in_sizes, int n_in,
                              void* d_out, int out_size, void* d_ws, size_t ws_size,
                              hipStream_t stream) {
    const float* x    = (const float*)d_in[0];
    const float* h0   = (const float*)d_in[1];
    const float* encW = (const float*)d_in[2];
    const float* encb = (const float*)d_in[3];
    const float* Wih  = (const float*)d_in[4];
    const float* Whh  = (const float*)d_in[5];
    const float* bih  = (const float*)d_in[6];
    const float* bhh  = (const float*)d_in[7];
    const float* decW = (const float*)d_in[8];
    const float* decb = (const float*)d_in[9];
    float* out = (float*)d_out;

    float* vec0 = (float*)d_ws;      // [H]
    float* vec1 = vec0 + H;          // [H]

    // 1) encoder: [1,1024] -> [1,2048]
    gemv_kernel<DIN><<<H / 4, 256, 0, stream>>>(encW, x, encb, vec0, H);
    // 2) sequential fused GRU layers, ping-pong carry
    const float* cin = vec0;
    float* cout = vec1;
    for (int l = 0; l < NL; ++l) {
        gru_layer_kernel<<<H / 4, 256, 0, stream>>>(
            Wih + (size_t)l * 3 * H * H, Whh + (size_t)l * 3 * H * H,
            bih + l * 3 * H, bhh + l * 3 * H,
            h0 + l * H, cin, cout, out + DOUT + l * H);
        float* t = cout; cout = (float*)cin; cin = t;
    }
    // 3) decoder: [1,2048] -> [1,1024]
    gemv_kernel<H><<<DOUT / 4, 256, 0, stream>>>(decW, cin, decb, out, DOUT);
}